// Round 9
// baseline (201.066 us; speedup 1.0000x reference)
//
#include <hip/hip_runtime.h>

// Shapes: N=8, M=2048 -> 16384 rows; D=128, L=128.
// out0 h: (16384,128) fp32; out1 edge: (8,2048,2048) = e[row] broadcast.
//
// R8 post-mortem: fragment-order weights won -9.3us (gather model right).
// Remaining ~17us over the ~24us traffic floor: every __syncthreads emits
// s_waitcnt vmcnt(0); with L2 saturated, store-ACK rate == HBM rate, so each
// round's 128KB/block edge stores force-drain at the next barrier.
// R9: BARRIER-FREE design. One WAVE per 16-row tile, end-to-end:
//   - x loaded global->registers directly in A-fragment layout
//   - fragment-layout transposes via per-wave PRIVATE LDS (lgkmcnt only)
//   - edge stores fire-and-forget; no vmcnt(0) exists in the kernel, so
//     stores stream at HBM BW under all remaining compute + kernel tail.

typedef short short8 __attribute__((ext_vector_type(8)));
typedef float floatx4 __attribute__((ext_vector_type(4)));

__device__ __forceinline__ short f2bf(float f) {
    union { float f; unsigned u; } v; v.f = f;
    unsigned r = v.u + 0x7fffu + ((v.u >> 16) & 1u);   // RNE
    return (short)(r >> 16);
}

// d_ws (shorts), all in MFMA-fragment order (unchanged from R8):
//   W1S at 0      (64KB): idx = ((ct*4+k)*64 + l)*8 + j, ct 0..15, k 0..3
//   W2S at 32768  (64KB): idx = ((ct*8+k)*64 + l)*8 + j, ct 0..7,  k 0..7
//   WES at 65536  (32KB): idx = ((ct*4+k)*64 + l)*8 + j, ct 0..7,  k 0..3
// Requires ws_size >= 163840 bytes.
__global__ __launch_bounds__(256)
void prep_weights(const float* __restrict__ w1n, const float* __restrict__ w2n,
                  const float* __restrict__ w1e, short* __restrict__ ws)
{
    const int id = blockIdx.x * 256 + threadIdx.x;   // 0..81919
    const int j = id & 7;
    if (id < 32768) {
        const int g = id >> 3, l = g & 63, ctk = g >> 6;
        const int ct = ctk >> 2, k = ctk & 3;
        const int kg = k * 32 + (l >> 4) * 8 + j;
        ws[id] = f2bf(w1n[kg * 256 + ct * 16 + (l & 15)]);
    } else if (id < 65536) {
        const int g = (id - 32768) >> 3, l = g & 63, ctk = g >> 6;
        const int ct = ctk >> 3, k = ctk & 7;
        const int kg = k * 32 + (l >> 4) * 8 + j;
        ws[id] = f2bf(w2n[kg * 128 + ct * 16 + (l & 15)]);
    } else {
        const int g = (id - 65536) >> 3, l = g & 63, ctk = g >> 6;
        const int ct = ctk >> 2, k = ctk & 3;
        const int kg = k * 32 + (l >> 4) * 8 + j;
        ws[id] = f2bf(w1e[kg * 128 + ct * 16 + (l & 15)]
                      + w1e[(kg + 128) * 128 + ct * 16 + (l & 15)]);
    }
}

#define TPB 256          // 4 waves/block
#define H1_STRIDE 264    // 256 + 8 pad
#define HB_STRIDE 136    // 128 + 8 pad

// MFMA 16x16x32 bf16 lane mapping:
//   A: lane holds A[m = lane&15][k = (lane>>4)*8 + j], j=0..7
//   B: lane holds B[k = (lane>>4)*8 + j][n = lane&15]
//   C/D: reg r holds D[row = (lane>>4)*4 + r][col = lane&15]
__global__ __launch_bounds__(TPB, 1)
void fused_wavetile(const float* __restrict__ x,
                    const float* __restrict__ b1n, const float* __restrict__ b2n,
                    const float* __restrict__ b1e,
                    const float* __restrict__ w2e, const float* __restrict__ b2e,
                    const short* __restrict__ wt,
                    float* __restrict__ h_out, float* __restrict__ edge_out)
{
    // per-wave private slices; NO __syncthreads in this kernel
    __shared__ short h1s_all[4 * 16 * H1_STRIDE];   // 33 KB
    __shared__ short hbs_all[4 * 16 * HB_STRIDE];   // 17 KB
    __shared__ float es_all[4 * 16];

    const int t = threadIdx.x;
    const int wave = t >> 6;
    const int l = t & 63;
    const int l15 = l & 15;
    const int quad = l >> 4;
    const int row0 = (blockIdx.x * 4 + wave) * 16;   // 1024 tiles, one per wave

    short* __restrict__ h1w = h1s_all + wave * 16 * H1_STRIDE;
    short* __restrict__ hbw = hbs_all + wave * 16 * HB_STRIDE;
    float* __restrict__ esw = es_all + wave * 16;

    const short* __restrict__ W2S = wt + 32768;
    const short* __restrict__ WES = wt + 65536;

    // ---- x -> A-fragments directly (lane reads 8 consecutive fp32 per k) ----
    short8 a1[4];
#pragma unroll
    for (int k = 0; k < 4; ++k) {
        const float* p = x + (size_t)(row0 + l15) * 128 + k * 32 + quad * 8;
        const float4 v0 = *(const float4*)p;
        const float4 v1 = *(const float4*)(p + 4);
        short8 a;
        a[0] = f2bf(v0.x); a[1] = f2bf(v0.y); a[2] = f2bf(v0.z); a[3] = f2bf(v0.w);
        a[4] = f2bf(v1.x); a[5] = f2bf(v1.y); a[6] = f2bf(v1.z); a[7] = f2bf(v1.w);
        a1[k] = a;
    }

    // ---- stage 1: h1 = relu(X @ W1n + b1n)   (16x128)@(128x256), 64 MFMA ----
#pragma unroll
    for (int ct = 0; ct < 16; ++ct) {
        const float b = b1n[ct * 16 + l15];
        floatx4 acc = (floatx4){b, b, b, b};
#pragma unroll
        for (int k = 0; k < 4; ++k) {
            const short8 bf = *(const short8*)(wt + ((ct * 4 + k) * 64 + l) * 8);
            acc = __builtin_amdgcn_mfma_f32_16x16x32_bf16(a1[k], bf, acc, 0, 0, 0);
        }
#pragma unroll
        for (int r = 0; r < 4; ++r)
            h1w[(quad * 4 + r) * H1_STRIDE + ct * 16 + l15] = f2bf(fmaxf(acc[r], 0.f));
    }
    // same-wave ds_write -> ds_read: lgkmcnt dependency only, no barrier

    // ---- stage 2: h = h1 @ W2n + b2n   (16x256)@(256x128), 64 MFMA ----
    short8 a2[8];
#pragma unroll
    for (int k = 0; k < 8; ++k)
        a2[k] = *(const short8*)&h1w[l15 * H1_STRIDE + k * 32 + quad * 8];

#pragma unroll
    for (int ct = 0; ct < 8; ++ct) {
        const float b = b2n[ct * 16 + l15];
        floatx4 acc = (floatx4){b, b, b, b};
#pragma unroll
        for (int k = 0; k < 8; ++k) {
            const short8 bf = *(const short8*)(W2S + ((ct * 8 + k) * 64 + l) * 8);
            acc = __builtin_amdgcn_mfma_f32_16x16x32_bf16(a2[k], bf, acc, 0, 0, 0);
        }
#pragma unroll
        for (int r = 0; r < 4; ++r) {
            const int row = quad * 4 + r;
            h_out[(size_t)(row0 + row) * 128 + ct * 16 + l15] = acc[r];
            hbw[row * HB_STRIDE + ct * 16 + l15] = f2bf(acc[r]);
        }
    }

    // ---- stage 3+4: t1 = relu(h @ WE + b1e); e = (t1 . w2e + b2e)/2048 ----
    short8 a3[4];
#pragma unroll
    for (int k = 0; k < 4; ++k)
        a3[k] = *(const short8*)&hbw[l15 * HB_STRIDE + k * 32 + quad * 8];

    float p[4] = {0.f, 0.f, 0.f, 0.f};
#pragma unroll
    for (int ct = 0; ct < 8; ++ct) {
        const float b = b1e[ct * 16 + l15];
        floatx4 acc = (floatx4){b, b, b, b};
#pragma unroll
        for (int k = 0; k < 4; ++k) {
            const short8 bf = *(const short8*)(WES + ((ct * 4 + k) * 64 + l) * 8);
            acc = __builtin_amdgcn_mfma_f32_16x16x32_bf16(a3[k], bf, acc, 0, 0, 0);
        }
        const float wv = w2e[ct * 16 + l15];
#pragma unroll
        for (int r = 0; r < 4; ++r)
            p[r] += fmaxf(acc[r], 0.f) * wv;
    }
#pragma unroll
    for (int off = 8; off >= 1; off >>= 1)
#pragma unroll
        for (int r = 0; r < 4; ++r)
            p[r] += __shfl_xor(p[r], off, 64);
    if (l15 == 0) {
        const float bb = b2e[0];
#pragma unroll
        for (int r = 0; r < 4; ++r)
            esw[quad * 4 + r] = (p[r] + bb) * (1.0f / 2048.0f);
    }
    // same-wave LDS write -> read (lgkmcnt only)

    // ---- stage 5: edge broadcast, 16 rows x 8KB, fire-and-forget ----
    {
        floatx4* __restrict__ e4 = (floatx4*)(edge_out + (size_t)row0 * 2048);
#pragma unroll
        for (int r = 0; r < 16; ++r) {
            const float ev = esw[r];
            const floatx4 vv = (floatx4){ev, ev, ev, ev};
#pragma unroll
            for (int i = 0; i < 8; ++i)
                e4[r * 512 + i * 64 + l] = vv;
        }
    }
}

extern "C" void kernel_launch(void* const* d_in, const int* in_sizes, int n_in,
                              void* d_out, int out_size, void* d_ws, size_t ws_size,
                              hipStream_t stream) {
    const float* x   = (const float*)d_in[0];
    const float* w1n = (const float*)d_in[1];
    const float* b1n = (const float*)d_in[2];
    const float* w2n = (const float*)d_in[3];
    const float* b2n = (const float*)d_in[4];
    const float* w1e = (const float*)d_in[5];
    const float* b1e = (const float*)d_in[6];
    const float* w2e = (const float*)d_in[7];
    const float* b2e = (const float*)d_in[8];

    float* h_out    = (float*)d_out;                              // (8,2048,128)
    float* edge_out = (float*)d_out + (size_t)8 * 2048 * 128;     // (8,2048,2048)
    short* wt       = (short*)d_ws;                               // 160 KB swizzled bf16 weights

    prep_weights<<<dim3(320), dim3(256), 0, stream>>>(w1n, w2n, w1e, wt);
    fused_wavetile<<<dim3(256), dim3(TPB), 0, stream>>>(
        x, b1n, b2n, b1e, w2e, b2e, wt, h_out, edge_out);
}

// Round 10
// 168.379 us; speedup vs baseline: 1.1941x; 1.1941x over previous
//
#include <hip/hip_runtime.h>

// Shapes: N=8, M=2048 -> 16384 rows; D=128, L=128.
// out0 h: (16384,128) fp32; out1 edge: (8,2048,2048) = e[row] broadcast.
//
// R9 post-mortem: barrier-free wave-tile collapsed occupancy (grid=1 block/CU,
// 1 wave/SIMD) -> all latency exposed, 77us. Barrier-drain model still holds
// (R8=41us fits 2x(9 compute + 11.5 forced drain)).
// R10: 2-wave blocks, 16-row tile, grid=1024 (6 waves/CU). ALL global stores
// issued strictly AFTER the last __syncthreads; everything after that barrier
// is LDS/register-only (stage-3 weights staged in LDS, biases in registers),
// so vmcnt (stores) never blocks compute. Barriers only drain loads = free.

typedef short short8 __attribute__((ext_vector_type(8)));
typedef float floatx4 __attribute__((ext_vector_type(4)));
typedef int int4v __attribute__((ext_vector_type(4)));

__device__ __forceinline__ short f2bf(float f) {
    union { float f; unsigned u; } v; v.f = f;
    unsigned r = v.u + 0x7fffu + ((v.u >> 16) & 1u);   // RNE
    return (short)(r >> 16);
}

// d_ws (shorts), all in MFMA-fragment order (unchanged from R8):
//   W1S at 0      (64KB): idx = ((ct*4+k)*64 + l)*8 + j, ct 0..15, k 0..3
//   W2S at 32768  (64KB): idx = ((ct*8+k)*64 + l)*8 + j, ct 0..7,  k 0..7
//   WES at 65536  (32KB): idx = ((ct*4+k)*64 + l)*8 + j, ct 0..7,  k 0..3
// Requires ws_size >= 163840 bytes.
__global__ __launch_bounds__(256)
void prep_weights(const float* __restrict__ w1n, const float* __restrict__ w2n,
                  const float* __restrict__ w1e, short* __restrict__ ws)
{
    const int id = blockIdx.x * 256 + threadIdx.x;   // 0..81919
    const int j = id & 7;
    if (id < 32768) {
        const int g = id >> 3, l = g & 63, ctk = g >> 6;
        const int ct = ctk >> 2, k = ctk & 3;
        const int kg = k * 32 + (l >> 4) * 8 + j;
        ws[id] = f2bf(w1n[kg * 256 + ct * 16 + (l & 15)]);
    } else if (id < 65536) {
        const int g = (id - 32768) >> 3, l = g & 63, ctk = g >> 6;
        const int ct = ctk >> 3, k = ctk & 7;
        const int kg = k * 32 + (l >> 4) * 8 + j;
        ws[id] = f2bf(w2n[kg * 128 + ct * 16 + (l & 15)]);
    } else {
        const int g = (id - 65536) >> 3, l = g & 63, ctk = g >> 6;
        const int ct = ctk >> 2, k = ctk & 3;
        const int kg = k * 32 + (l >> 4) * 8 + j;
        ws[id] = f2bf(w1e[kg * 128 + ct * 16 + (l & 15)]
                      + w1e[(kg + 128) * 128 + ct * 16 + (l & 15)]);
    }
}

#define TPB 128          // 2 waves/block
#define H1_STRIDE 264    // 256 + 8 pad
#define HB_STRIDE 136    // 128 + 8 pad

// MFMA 16x16x32 bf16 lane mapping:
//   A: lane holds A[m = lane&15][k = (lane>>4)*8 + j], j=0..7
//   B: lane holds B[k = (lane>>4)*8 + j][n = lane&15]
//   C/D: reg r holds D[row = (lane>>4)*4 + r][col = lane&15]
__global__ __launch_bounds__(TPB, 2)
void fused_pairwave(const float* __restrict__ x,
                    const float* __restrict__ b1n, const float* __restrict__ b2n,
                    const float* __restrict__ b1e,
                    const float* __restrict__ w2e, const float* __restrict__ b2e,
                    const short* __restrict__ wt,
                    float* __restrict__ h_out, float* __restrict__ edge_out)
{
    __shared__ short h1s[16 * H1_STRIDE];   // 8.4 KB
    __shared__ short hbs[16 * HB_STRIDE];   // 4.4 KB
    __shared__ short wes[16384];            // 32 KB stage-3 weights (frag order)
    __shared__ float es_all[2][8];

    const int t = threadIdx.x;
    const int w = t >> 6;          // wave 0..1
    const int l = t & 63;
    const int l15 = l & 15;
    const int quad = l >> 4;
    const int row0 = blockIdx.x * 16;   // 1024 blocks, one 16-row tile each

    // ---- WES -> LDS (2048 int4, 16/thread), issued first, loads only ----
    {
        const int4v* __restrict__ src = (const int4v*)(wt + 65536);
        int4v* dst = (int4v*)wes;
#pragma unroll
        for (int i = 0; i < 16; ++i)
            dst[t + i * TPB] = src[t + i * TPB];
    }

    // ---- preload stage-3/4 scalars into registers (loads only) ----
    float be[8], wv[8];
#pragma unroll
    for (int ct = 0; ct < 8; ++ct) {
        be[ct] = b1e[ct * 16 + l15];
        wv[ct] = w2e[ct * 16 + l15];
    }
    const float b2e0 = b2e[0];

    // ---- x -> A-fragments directly (both waves load same 16 rows) ----
    short8 a1[4];
#pragma unroll
    for (int k = 0; k < 4; ++k) {
        const float* p = x + (size_t)(row0 + l15) * 128 + k * 32 + quad * 8;
        const float4 v0 = *(const float4*)p;
        const float4 v1 = *(const float4*)(p + 4);
        short8 a;
        a[0] = f2bf(v0.x); a[1] = f2bf(v0.y); a[2] = f2bf(v0.z); a[3] = f2bf(v0.w);
        a[4] = f2bf(v1.x); a[5] = f2bf(v1.y); a[6] = f2bf(v1.z); a[7] = f2bf(v1.w);
        a1[k] = a;
    }

    // ---- stage 1: h1 = relu(X @ W1n + b1n), 8 col-tiles per wave ----
#pragma unroll
    for (int ci = 0; ci < 8; ++ci) {
        const int ct = w * 8 + ci;
        const float b = b1n[ct * 16 + l15];
        floatx4 acc = (floatx4){b, b, b, b};
#pragma unroll
        for (int k = 0; k < 4; ++k) {
            const short8 bf = *(const short8*)(wt + ((ct * 4 + k) * 64 + l) * 8);
            acc = __builtin_amdgcn_mfma_f32_16x16x32_bf16(a1[k], bf, acc, 0, 0, 0);
        }
#pragma unroll
        for (int r = 0; r < 4; ++r)
            h1s[(quad * 4 + r) * H1_STRIDE + ct * 16 + l15] = f2bf(fmaxf(acc[r], 0.f));
    }
    __syncthreads();   // barrier #1: outstanding VMEM = loads only -> cheap

    // ---- stage 2: h = h1 @ W2n + b2n, 4 col-tiles per wave ----
    short8 a2[8];
#pragma unroll
    for (int k = 0; k < 8; ++k)
        a2[k] = *(const short8*)&h1s[l15 * H1_STRIDE + k * 32 + quad * 8];

    const short* __restrict__ W2S = wt + 32768;
    floatx4 acc2[4];
#pragma unroll
    for (int ci = 0; ci < 4; ++ci) {
        const int ct = w * 4 + ci;
        const float b = b2n[ct * 16 + l15];
        floatx4 acc = (floatx4){b, b, b, b};
#pragma unroll
        for (int k = 0; k < 8; ++k) {
            const short8 bf = *(const short8*)(W2S + ((ct * 8 + k) * 64 + l) * 8);
            acc = __builtin_amdgcn_mfma_f32_16x16x32_bf16(a2[k], bf, acc, 0, 0, 0);
        }
        acc2[ci] = acc;
#pragma unroll
        for (int r = 0; r < 4; ++r)
            hbs[(quad * 4 + r) * HB_STRIDE + ct * 16 + l15] = f2bf(acc[r]);
    }
    __syncthreads();   // barrier #2 (LAST): still loads only outstanding

    // ======== from here on: NO barriers; global stores can never be
    // ======== force-drained; compute uses only LDS + registers.

    // ---- h_out stores (fp32, from registers) ----
#pragma unroll
    for (int ci = 0; ci < 4; ++ci) {
        const int ct = w * 4 + ci;
#pragma unroll
        for (int r = 0; r < 4; ++r)
            h_out[(size_t)(row0 + quad * 4 + r) * 128 + ct * 16 + l15] = acc2[ci][r];
    }

    // ---- stage 3+4 (row-split: wave w owns rows w*8..w*8+7) ----
    short8 a3[4];
#pragma unroll
    for (int k = 0; k < 4; ++k)
        a3[k] = *(const short8*)&hbs[(w * 8 + (l15 & 7)) * HB_STRIDE + k * 32 + quad * 8];

    float p[4] = {0.f, 0.f, 0.f, 0.f};
#pragma unroll
    for (int ct = 0; ct < 8; ++ct) {
        const float b = be[ct];
        floatx4 acc = (floatx4){b, b, b, b};
#pragma unroll
        for (int k = 0; k < 4; ++k) {
            const short8 bf = *(const short8*)&wes[((ct * 4 + k) * 64 + l) * 8];
            acc = __builtin_amdgcn_mfma_f32_16x16x32_bf16(a3[k], bf, acc, 0, 0, 0);
        }
#pragma unroll
        for (int r = 0; r < 4; ++r)
            p[r] += fmaxf(acc[r], 0.f) * wv[ct];
    }
    // butterfly over the 16 lanes of each l15-group (D rows m and m+8 duplicate)
#pragma unroll
    for (int off = 8; off >= 1; off >>= 1)
#pragma unroll
        for (int r = 0; r < 4; ++r)
            p[r] += __shfl_xor(p[r], off, 64);
    if (l15 == 0 && quad < 2) {
#pragma unroll
        for (int r = 0; r < 4; ++r)
            es_all[w][quad * 4 + r] = (p[r] + b2e0) * (1.0f / 2048.0f);
    }
    // wave-private LDS write -> read: lgkmcnt only

    // ---- stage 5: edge rows w*8..w*8+7, 64 x 1KB contiguous stores ----
    {
        floatx4* __restrict__ e4 = (floatx4*)(edge_out + (size_t)row0 * 2048);
#pragma unroll
        for (int rr = 0; rr < 8; ++rr) {
            const float ev = es_all[w][rr];
            const floatx4 vv = (floatx4){ev, ev, ev, ev};
            const int base = (w * 8 + rr) * 512;
#pragma unroll
            for (int i = 0; i < 8; ++i)
                e4[base + i * 64 + l] = vv;
        }
    }
}

extern "C" void kernel_launch(void* const* d_in, const int* in_sizes, int n_in,
                              void* d_out, int out_size, void* d_ws, size_t ws_size,
                              hipStream_t stream) {
    const float* x   = (const float*)d_in[0];
    const float* w1n = (const float*)d_in[1];
    const float* b1n = (const float*)d_in[2];
    const float* w2n = (const float*)d_in[3];
    const float* b2n = (const float*)d_in[4];
    const float* w1e = (const float*)d_in[5];
    const float* b1e = (const float*)d_in[6];
    const float* w2e = (const float*)d_in[7];
    const float* b2e = (const float*)d_in[8];

    float* h_out    = (float*)d_out;                              // (8,2048,128)
    float* edge_out = (float*)d_out + (size_t)8 * 2048 * 128;     // (8,2048,2048)
    short* wt       = (short*)d_ws;                               // 160 KB swizzled bf16 weights

    prep_weights<<<dim3(320), dim3(256), 0, stream>>>(w1n, w2n, w1e, wt);
    fused_pairwave<<<dim3(1024), dim3(TPB), 0, stream>>>(
        x, b1n, b2n, b1e, w2e, b2e, wt, h_out, edge_out);
}

// Round 11
// 158.195 us; speedup vs baseline: 1.2710x; 1.0644x over previous
//
#include <hip/hip_runtime.h>

// Shapes: N=8, M=2048 -> 16384 rows; D=128, L=128.
// out0 h: (16384,128) fp32; out1 edge: (8,2048,2048) = e[row] broadcast.
//
// R10 post-mortem: fire-and-forget stores don't fix the drain (implicit
// end-of-block vmcnt(0) + L2 writeback backlog). Model fit across R1..R10:
// overhead 123.5 + prep 2 + compute + edge-drain. Untested cell:
// R6's SPLIT structure x R8's fragment-order weights.
// R11: compute kernel (R8 MFMA body, grid 1024, writes h + e scalars only,
// ~10us) then pure broadcast kernel (fill-shaped streaming, ~22us).

typedef short short8 __attribute__((ext_vector_type(8)));
typedef float floatx4 __attribute__((ext_vector_type(4)));

__device__ __forceinline__ short f2bf(float f) {
    union { float f; unsigned u; } v; v.f = f;
    unsigned r = v.u + 0x7fffu + ((v.u >> 16) & 1u);   // RNE
    return (short)(r >> 16);
}

// d_ws: shorts in MFMA-fragment order (unchanged from R8):
//   W1S at 0      (64KB): idx = ((ct*4+k)*64 + l)*8 + j, ct 0..15, k 0..3
//   W2S at 32768  (64KB): idx = ((ct*8+k)*64 + l)*8 + j, ct 0..7,  k 0..7
//   WES at 65536  (32KB): idx = ((ct*4+k)*64 + l)*8 + j, ct 0..7,  k 0..3
//   float es[16384] at byte 163840 (64KB)
// Requires ws_size >= 229376 bytes.
__global__ __launch_bounds__(256)
void prep_weights(const float* __restrict__ w1n, const float* __restrict__ w2n,
                  const float* __restrict__ w1e, short* __restrict__ ws)
{
    const int id = blockIdx.x * 256 + threadIdx.x;   // 0..81919
    const int j = id & 7;
    if (id < 32768) {
        const int g = id >> 3, l = g & 63, ctk = g >> 6;
        const int ct = ctk >> 2, k = ctk & 3;
        const int kg = k * 32 + (l >> 4) * 8 + j;
        ws[id] = f2bf(w1n[kg * 256 + ct * 16 + (l & 15)]);
    } else if (id < 65536) {
        const int g = (id - 32768) >> 3, l = g & 63, ctk = g >> 6;
        const int ct = ctk >> 3, k = ctk & 7;
        const int kg = k * 32 + (l >> 4) * 8 + j;
        ws[id] = f2bf(w2n[kg * 128 + ct * 16 + (l & 15)]);
    } else {
        const int g = (id - 65536) >> 3, l = g & 63, ctk = g >> 6;
        const int ct = ctk >> 2, k = ctk & 3;
        const int kg = k * 32 + (l >> 4) * 8 + j;
        ws[id] = f2bf(w1e[kg * 128 + ct * 16 + (l & 15)]
                      + w1e[(kg + 128) * 128 + ct * 16 + (l & 15)]);
    }
}

#define TPB 256
#define H1_STRIDE 264    // 256 + 8 pad
#define HB_STRIDE 136    // 128 + 8 pad

// MFMA 16x16x32 bf16 lane mapping:
//   A: lane holds A[m = lane&15][k = (lane>>4)*8 + j], j=0..7
//   B: lane holds B[k = (lane>>4)*8 + j][n = lane&15]
//   C/D: reg r holds D[row = (lane>>4)*4 + r][col = lane&15]
__global__ __launch_bounds__(TPB, 4)
void node_compute(const float* __restrict__ x,
                  const float* __restrict__ b1n, const float* __restrict__ b2n,
                  const float* __restrict__ b1e,
                  const float* __restrict__ w2e, const float* __restrict__ b2e,
                  const short* __restrict__ wt,
                  float* __restrict__ h_out, float* __restrict__ e_ws)
{
    __shared__ short h1s[16 * H1_STRIDE];   // 8.4 KB
    __shared__ short hbs[16 * HB_STRIDE];   // 4.4 KB
    __shared__ float partial[4][16];

    const int t = threadIdx.x;
    const int w = t >> 6;          // wave 0..3
    const int l = t & 63;
    const int l15 = l & 15;
    const int quad = l >> 4;
    const int row0 = blockIdx.x * 16;   // 1024 blocks, one 16-row tile each

    const short* __restrict__ W2S = wt + 32768;
    const short* __restrict__ WES = wt + 65536;

    // ---- x -> A-fragments directly (verified in R9/R10) ----
    short8 a1[4];
#pragma unroll
    for (int k = 0; k < 4; ++k) {
        const float* p = x + (size_t)(row0 + l15) * 128 + k * 32 + quad * 8;
        const float4 v0 = *(const float4*)p;
        const float4 v1 = *(const float4*)(p + 4);
        short8 a;
        a[0] = f2bf(v0.x); a[1] = f2bf(v0.y); a[2] = f2bf(v0.z); a[3] = f2bf(v0.w);
        a[4] = f2bf(v1.x); a[5] = f2bf(v1.y); a[6] = f2bf(v1.z); a[7] = f2bf(v1.w);
        a1[k] = a;
    }

    // ---- stage 1: h1 = relu(X @ W1n + b1n), 4 col-tiles per wave ----
#pragma unroll
    for (int ci = 0; ci < 4; ++ci) {
        const int ct = 4 * w + ci;
        const float b = b1n[ct * 16 + l15];
        floatx4 acc = (floatx4){b, b, b, b};
#pragma unroll
        for (int k = 0; k < 4; ++k) {
            const short8 bf = *(const short8*)(wt + ((ct * 4 + k) * 64 + l) * 8);
            acc = __builtin_amdgcn_mfma_f32_16x16x32_bf16(a1[k], bf, acc, 0, 0, 0);
        }
#pragma unroll
        for (int r = 0; r < 4; ++r)
            h1s[(quad * 4 + r) * H1_STRIDE + ct * 16 + l15] = f2bf(fmaxf(acc[r], 0.f));
    }
    __syncthreads();

    // ---- stage 2: h = h1 @ W2n + b2n, 2 col-tiles per wave ----
    short8 a2[8];
#pragma unroll
    for (int k = 0; k < 8; ++k)
        a2[k] = *(const short8*)&h1s[l15 * H1_STRIDE + k * 32 + quad * 8];

#pragma unroll
    for (int ci = 0; ci < 2; ++ci) {
        const int ct = 2 * w + ci;
        const float b = b2n[ct * 16 + l15];
        floatx4 acc = (floatx4){b, b, b, b};
#pragma unroll
        for (int k = 0; k < 8; ++k) {
            const short8 bf = *(const short8*)(W2S + ((ct * 8 + k) * 64 + l) * 8);
            acc = __builtin_amdgcn_mfma_f32_16x16x32_bf16(a2[k], bf, acc, 0, 0, 0);
        }
#pragma unroll
        for (int r = 0; r < 4; ++r) {
            const int row = quad * 4 + r;
            h_out[(size_t)(row0 + row) * 128 + ct * 16 + l15] = acc[r];
            hbs[row * HB_STRIDE + ct * 16 + l15] = f2bf(acc[r]);
        }
    }
    __syncthreads();

    // ---- stage 3+4: t1 = relu(h @ WE + b1e); e = (t1 . w2e + b2e)/2048 ----
    short8 a3[4];
#pragma unroll
    for (int k = 0; k < 4; ++k)
        a3[k] = *(const short8*)&hbs[l15 * HB_STRIDE + k * 32 + quad * 8];

    float p[4] = {0.f, 0.f, 0.f, 0.f};
#pragma unroll
    for (int ci = 0; ci < 2; ++ci) {
        const int ct = 2 * w + ci;
        const float b = b1e[ct * 16 + l15];
        floatx4 acc = (floatx4){b, b, b, b};
#pragma unroll
        for (int k = 0; k < 4; ++k) {
            const short8 bf = *(const short8*)(WES + ((ct * 4 + k) * 64 + l) * 8);
            acc = __builtin_amdgcn_mfma_f32_16x16x32_bf16(a3[k], bf, acc, 0, 0, 0);
        }
        const float wv = w2e[ct * 16 + l15];
#pragma unroll
        for (int r = 0; r < 4; ++r)
            p[r] += fmaxf(acc[r], 0.f) * wv;
    }
#pragma unroll
    for (int off = 8; off >= 1; off >>= 1)
#pragma unroll
        for (int r = 0; r < 4; ++r)
            p[r] += __shfl_xor(p[r], off, 64);
    if (l15 == 0) {
#pragma unroll
        for (int r = 0; r < 4; ++r)
            partial[w][quad * 4 + r] = p[r];
    }
    __syncthreads();
    if (t < 16) {
        e_ws[row0 + t] = (partial[0][t] + partial[1][t] + partial[2][t]
                          + partial[3][t] + b2e[0]) * (1.0f / 2048.0f);
    }
}

// ---- pure streaming broadcast: 2048 blocks x 256 thr, 2 rows (16KB) per
// block, 4 coalesced float4 stores/thread -- the proven fill shape. ----
__global__ __launch_bounds__(256)
void edge_broadcast(const float* __restrict__ es, float* __restrict__ edge_out)
{
    const int t = threadIdx.x;
    const int r0 = blockIdx.x * 2;
    const float v0 = es[r0];          // block-uniform -> scalar loads
    const float v1 = es[r0 + 1];
    floatx4* __restrict__ e4 = (floatx4*)(edge_out + (size_t)r0 * 2048);
    const floatx4 a = (floatx4){v0, v0, v0, v0};
    const floatx4 b = (floatx4){v1, v1, v1, v1};
    e4[t] = a;
    e4[t + 256] = a;
    e4[t + 512] = b;
    e4[t + 768] = b;
}

extern "C" void kernel_launch(void* const* d_in, const int* in_sizes, int n_in,
                              void* d_out, int out_size, void* d_ws, size_t ws_size,
                              hipStream_t stream) {
    const float* x   = (const float*)d_in[0];
    const float* w1n = (const float*)d_in[1];
    const float* b1n = (const float*)d_in[2];
    const float* w2n = (const float*)d_in[3];
    const float* b2n = (const float*)d_in[4];
    const float* w1e = (const float*)d_in[5];
    const float* b1e = (const float*)d_in[6];
    const float* w2e = (const float*)d_in[7];
    const float* b2e = (const float*)d_in[8];

    float* h_out    = (float*)d_out;                              // (8,2048,128)
    float* edge_out = (float*)d_out + (size_t)8 * 2048 * 128;     // (8,2048,2048)
    short* wt       = (short*)d_ws;                               // 160 KB swizzled bf16 weights
    float* e_ws     = (float*)((char*)d_ws + 163840);             // 64 KB e scalars

    prep_weights<<<dim3(320), dim3(256), 0, stream>>>(w1n, w2n, w1e, wt);
    node_compute<<<dim3(1024), dim3(TPB), 0, stream>>>(
        x, b1n, b2n, b1e, w2e, b2e, wt, h_out, e_ws);
    edge_broadcast<<<dim3(2048), dim3(256), 0, stream>>>(e_ws, edge_out);
}